// Round 13
// baseline (794.938 us; speedup 1.0000x reference)
//
#include <hip/hip_runtime.h>
#include <hip/hip_bf16.h>
#include <hip/hip_fp16.h>

#define DELTA 2.5749f
#define BN_EPS 1e-5f

typedef __attribute__((ext_vector_type(8))) _Float16 f16x8;
typedef __attribute__((ext_vector_type(2))) _Float16 f16x2;
typedef __attribute__((ext_vector_type(4))) float f32x4;

__device__ inline unsigned short f2h(float f) {
    union { _Float16 h; unsigned short u; } v;
    v.h = (_Float16)f;  // RNE
    return v.u;
}

// ---------------------------------------------------------------- CSR build (XCD-partitioned)
__global__ __launch_bounds__(256) void k_degree(const int* __restrict__ dst,
                                                int* __restrict__ deg, int E, int npp) {
    int part = blockIdx.x & 7;
    int lo = part * npp, hi = lo + npp;
    int stride = (gridDim.x >> 3) * 256;
    for (int e = (blockIdx.x >> 3) * 256 + threadIdx.x; e < E; e += stride) {
        int d = dst[e];
        if (d >= lo && d < hi) atomicAdd(&deg[d], 1);
    }
}

#define SCAN_B 1024
__global__ void k_scan_block(const int* __restrict__ deg, int* __restrict__ excl,
                             int* __restrict__ bsums, int total) {
    __shared__ int s[SCAN_B];
    int t = threadIdx.x, i = blockIdx.x * SCAN_B + t;
    int v = (i < total) ? deg[i] : 0;
    s[t] = v; __syncthreads();
    for (int off = 1; off < SCAN_B; off <<= 1) {
        int x = (t >= off) ? s[t - off] : 0;
        __syncthreads();
        s[t] += x;
        __syncthreads();
    }
    if (i < total) excl[i] = s[t] - v;
    if (t == SCAN_B - 1) bsums[blockIdx.x] = s[t];
}

__global__ void k_scan_tops(int* __restrict__ bsums, int nb) {
    __shared__ int s[SCAN_B];
    int t = threadIdx.x;
    int v = (t < nb) ? bsums[t] : 0;
    s[t] = v; __syncthreads();
    for (int off = 1; off < SCAN_B; off <<= 1) {
        int x = (t >= off) ? s[t - off] : 0;
        __syncthreads();
        s[t] += x;
        __syncthreads();
    }
    if (t < nb) bsums[t] = s[t] - v;  // exclusive
}

__global__ void k_scan_add(int* __restrict__ excl, const int* __restrict__ bsums, int total) {
    int i = blockIdx.x * SCAN_B + threadIdx.x;
    if (i < total) excl[i] += bsums[blockIdx.x];
}

__global__ __launch_bounds__(256) void k_fill(const int* __restrict__ src,
                                              const int* __restrict__ dst,
                                              const int* __restrict__ rowptr,
                                              int* __restrict__ fill,
                                              int* __restrict__ col, int E, int npp) {
    int part = blockIdx.x & 7;
    int lo = part * npp, hi = lo + npp;
    int stride = (gridDim.x >> 3) * 256;
    for (int e = (blockIdx.x >> 3) * 256 + threadIdx.x; e < E; e += stride) {
        int d = dst[e];
        if (d >= lo && d < hi) {
            int pos = rowptr[d] + atomicAdd(&fill[d], 1);
            col[pos] = src[e];
        }
    }
}

// ---------------------------------------------------------------- weight cast f32 -> f16
__global__ void k_castw(const float* __restrict__ w, unsigned short* __restrict__ o, int n4) {
    int i = blockIdx.x * 256 + threadIdx.x;
    if (i < n4) {
        float4 v = ((const float4*)w)[i];
        ushort4 r;
        r.x = f2h(v.x); r.y = f2h(v.y); r.z = f2h(v.z); r.w = f2h(v.w);
        ((ushort4*)o)[i] = r;
    }
}

// ---------------------------------------------------------------- BN affine helpers
__global__ void k_ident(float* __restrict__ aff) {
    int t = threadIdx.x;  // 128
    aff[t] = (t < 64) ? 1.f : 0.f;
}

__global__ void k_bnfin(const float* __restrict__ stat, const float* __restrict__ gamma,
                        const float* __restrict__ beta, float* __restrict__ aff, float invN) {
    int d = threadIdx.x;  // 64
    float mu = stat[d] * invN;
    float var = stat[64 + d] * invN - mu * mu;
    float sc = rsqrtf(var + BN_EPS) * gamma[d];
    aff[d] = sc;
    aff[64 + d] = beta[d] - mu * sc;
}

// ---------------------------------------------------------------- aggregation
// 2 nodes per wave; lane owns an f16x2 feature pair across ALL edges of its
// node -> NO cross-lane reduction. Edge loop unrolled x8 for MLP.
// BN affine applied analytically in epilogue (sc>0 holds: gamma=1).
#define ACC2(V)                                                            \
    do {                                                                   \
        mx = __builtin_elementwise_max(mx, V);                             \
        float x0 = (float)V[0], x1 = (float)V[1];                          \
        sa += x0; qa = fmaf(x0, x0, qa);                                   \
        sb += x1; qb = fmaf(x1, x1, qb);                                   \
    } while (0)

__global__ __launch_bounds__(256) void k_agg(const unsigned short* __restrict__ h16,
                                             const int* __restrict__ rowptr,
                                             const int* __restrict__ col,
                                             const float* __restrict__ aff,
                                             unsigned short* __restrict__ baseF,
                                             float* __restrict__ cnt, int N) {
    int t = threadIdx.x;
    int lane = t & 63;
    int half = lane >> 5;          // which node of the wave's pair
    int fl = lane & 31;            // feature-pair index (feats fl*2, fl*2+1)
    int node = blockIdx.x * 8 + (t >> 6) * 2 + half;
    if (node >= N) return;
    const _Float16* hp = (const _Float16*)h16;
    int s0 = rowptr[node], s1 = rowptr[node + 1];
    int deg = s1 - s0;
    float sa = 0.f, sb = 0.f, qa = 0.f, qb = 0.f;
    f16x2 mx;
    mx[0] = (_Float16)(-65504.0f); mx[1] = (_Float16)(-65504.0f);
    int fo2 = fl * 2;
    int e = s0;
    for (; e + 7 < s1; e += 8) {
        int c0 = col[e], c1 = col[e + 1], c2 = col[e + 2], c3 = col[e + 3];
        int c4 = col[e + 4], c5 = col[e + 5], c6 = col[e + 6], c7 = col[e + 7];
        f16x2 v0 = *(const f16x2*)(hp + (size_t)c0 * 64 + fo2);
        f16x2 v1 = *(const f16x2*)(hp + (size_t)c1 * 64 + fo2);
        f16x2 v2 = *(const f16x2*)(hp + (size_t)c2 * 64 + fo2);
        f16x2 v3 = *(const f16x2*)(hp + (size_t)c3 * 64 + fo2);
        f16x2 v4 = *(const f16x2*)(hp + (size_t)c4 * 64 + fo2);
        f16x2 v5 = *(const f16x2*)(hp + (size_t)c5 * 64 + fo2);
        f16x2 v6 = *(const f16x2*)(hp + (size_t)c6 * 64 + fo2);
        f16x2 v7 = *(const f16x2*)(hp + (size_t)c7 * 64 + fo2);
        ACC2(v0); ACC2(v1); ACC2(v2); ACC2(v3);
        ACC2(v4); ACC2(v5); ACC2(v6); ACC2(v7);
    }
    for (; e < s1; ++e) {
        int c0 = col[e];
        f16x2 v0 = *(const f16x2*)(hp + (size_t)c0 * 64 + fo2);
        ACC2(v0);
    }
    float c = (float)(deg > 0 ? deg : 1);
    float ic = 1.f / c;
    float2 sc2 = *(const float2*)(aff + fo2);
    float2 sh2 = *(const float2*)(aff + 64 + fo2);
    float sum0, sum1, max0, max1, mean0, mean1, var0, var1;
    if (deg == 0) {
        sum0 = sum1 = max0 = max1 = mean0 = mean1 = var0 = var1 = 0.f;
    } else {
        sum0 = fmaf(sc2.x, sa, c * sh2.x);
        sum1 = fmaf(sc2.y, sb, c * sh2.y);
        max0 = fmaf(sc2.x, (float)mx[0], sh2.x);
        max1 = fmaf(sc2.y, (float)mx[1], sh2.y);
        float m0 = sa * ic, m1 = sb * ic;
        mean0 = fmaf(sc2.x, m0, sh2.x);
        mean1 = fmaf(sc2.y, m1, sh2.y);
        var0 = sc2.x * sc2.x * fmaxf(fmaf(-m0, m0, qa * ic), 0.f);
        var1 = sc2.y * sc2.y * fmaxf(fmaf(-m1, m1, qb * ic), 0.f);
    }
    size_t b = (size_t)node * 256 + fo2;
    ushort2 o;
    o.x = f2h(sum0); o.y = f2h(sum1);  *(ushort2*)(baseF + b) = o;
    o.x = f2h(max0); o.y = f2h(max1);  *(ushort2*)(baseF + b + 64) = o;
    o.x = f2h(mean0); o.y = f2h(mean1); *(ushort2*)(baseF + b + 128) = o;
    o.x = f2h(var0); o.y = f2h(var1);  *(ushort2*)(baseF + b + 192) = o;
    if (fl == 0) cnt[node] = c;
}

// ---------------------------------------------------------------- fused per-layer MLP
// LDS aliased by lifetime: region0[18KB] = ldsW(12KB, phase0) -> bufB(18KB,
// ph2-3) -> red(8KB, ph3-end, after barrier). bufA separate 18KB.
// Total 36864 B -> 4 blocks/CU (16 waves) vs previous 61440 (2 blocks).
// Phase0 uses 32-k chunks (8 chunks x 12 records x 1KB).
__global__ __launch_bounds__(256) void k_mlp(const unsigned short* __restrict__ baseF,
                                             const float* __restrict__ cnt,
                                             const unsigned short* __restrict__ mWF,
                                             const float* __restrict__ mb,
                                             const unsigned short* __restrict__ hres16,
                                             const float* __restrict__ aff,
                                             const unsigned short* __restrict__ w1F,
                                             const float* __restrict__ b1,
                                             const unsigned short* __restrict__ w2F,
                                             const float* __restrict__ b2,
                                             float* __restrict__ bnstat,
                                             unsigned short* __restrict__ hOut16, int N) {
    __shared__ char smem[36864];
    _Float16* ldsW = (_Float16*)smem;             // phase0: 12 KB
    _Float16* bufB = (_Float16*)smem;             // phases 2-3: 18 KB
    float* red = (float*)smem;                    // phase3-end: 8 KB (barrier-guarded)
    _Float16* bufA = (_Float16*)(smem + 18432);   // [128][72] f16

    int t = threadIdx.x;
    int wave = t >> 6, lane = t & 63;
    int r16 = lane & 15, quad = lane >> 4;
    int n0 = blockIdx.x * 128;
    int m0 = n0 + wave * 32;

    // ---------------- Phase 0: base[N,256] x 3 matrices (8 chunks of 32-k)
    const _Float16* aptr0 = (const _Float16*)baseF + (size_t)(m0 + r16) * 256 + quad * 8;
    const _Float16* aptr1 = aptr0 + 16 * 256;
    f32x4 acc0[12], acc1[12];
#pragma unroll
    for (int i = 0; i < 12; i++) {
        acc0[i] = (f32x4){0.f, 0.f, 0.f, 0.f};
        acc1[i] = (f32x4){0.f, 0.f, 0.f, 0.f};
    }
    f16x8 a0 = *(const f16x8*)(aptr0);
    f16x8 a1 = *(const f16x8*)(aptr1);

#pragma unroll 1
    for (int chunk = 0; chunk < 8; chunk++) {
        if (chunk) __syncthreads();  // prior chunk's reads done
        // stage 12 records (3 per wave): rec -> tile (mat,nt)
#pragma unroll
        for (int j = 0; j < 3; j++) {
            int rec = wave * 3 + j;
            int mat = rec >> 2, nt = rec & 3;
            uint4 v = *(const uint4*)(mWF + (size_t)(nt * 16 + r16) * 768 + mat * 256
                                      + chunk * 32 + quad * 8);
            *(uint4*)((unsigned short*)ldsW + rec * 512 + lane * 8) = v;
        }
        __syncthreads();
        f16x8 na0, na1;
        if (chunk < 7) {
            na0 = *(const f16x8*)(aptr0 + (chunk + 1) * 32);
            na1 = *(const f16x8*)(aptr1 + (chunk + 1) * 32);
        }
#pragma unroll
        for (int tile = 0; tile < 12; tile++) {
            f16x8 wF = *(const f16x8*)(ldsW + tile * 512 + lane * 8);
            acc0[tile] = __builtin_amdgcn_mfma_f32_16x16x32_f16(a0, wF, acc0[tile], 0, 0, 0);
            acc1[tile] = __builtin_amdgcn_mfma_f32_16x16x32_f16(a1, wF, acc1[tile], 0, 0, 0);
        }
        a0 = na0; a1 = na1;
    }
    __syncthreads();

    // ---------------- Phase 1a: residual copy into bufA (coalesced)
    {
        int nl = t >> 1, fo = (t & 1) * 32;
        int gn = n0 + nl;
        uint4* dp = (uint4*)(bufA + nl * 72 + fo);
        if (gn < N) {
            const uint4* sp = (const uint4*)(hres16 + (size_t)gn * 64 + fo);
            dp[0] = sp[0]; dp[1] = sp[1]; dp[2] = sp[2]; dp[3] = sp[3];
        } else {
            uint4 z = make_uint4(0, 0, 0, 0);
            dp[0] = z; dp[1] = z; dp[2] = z; dp[3] = z;
        }
    }
    __syncthreads();

    // ---------------- Phase 1b: combine accs + bias + scalers + affine residual
    float scf[4], shf[4], mbv[4];
#pragma unroll
    for (int nt = 0; nt < 4; nt++) {
        int f = nt * 16 + r16;
        scf[nt] = aff[f]; shf[nt] = aff[64 + f]; mbv[nt] = mb[f];
    }
#pragma unroll
    for (int mt = 0; mt < 2; mt++) {
#pragma unroll
        for (int i = 0; i < 4; i++) {
            int nl = wave * 32 + mt * 16 + quad * 4 + i;
            int gn = n0 + nl;
            if (gn < N) {
                float c = cnt[gn];
                float amp = c / DELTA, att = DELTA / c;
                f32x4* a = mt ? acc1 : acc0;
#pragma unroll
                for (int nt = 0; nt < 4; nt++) {
                    int f = nt * 16 + r16;
                    float r = (float)bufA[nl * 72 + f];
                    float v = a[nt][i] + amp * a[4 + nt][i] + att * a[8 + nt][i]
                            + mbv[nt] + fmaf(r, scf[nt], shf[nt]);
                    bufA[nl * 72 + f] = (_Float16)v;
                }
            }
        }
    }
    __syncthreads();

    // ---------------- Phase 2: nn1 (relu(t @ W1 + b1)) -> bufB
    f32x4 accN[8];
#pragma unroll
    for (int i = 0; i < 8; i++) accN[i] = (f32x4){0.f, 0.f, 0.f, 0.f};
#pragma unroll
    for (int s = 0; s < 2; s++) {
        f16x8 fA0 = *(const f16x8*)(bufA + (wave * 32 + r16) * 72 + s * 32 + quad * 8);
        f16x8 fA1 = *(const f16x8*)(bufA + (wave * 32 + 16 + r16) * 72 + s * 32 + quad * 8);
#pragma unroll
        for (int nt = 0; nt < 4; nt++) {
            f16x8 wB = *(const f16x8*)((const _Float16*)w1F + (size_t)(nt * 16 + r16) * 64
                                       + s * 32 + quad * 8);
            accN[nt]     = __builtin_amdgcn_mfma_f32_16x16x32_f16(fA0, wB, accN[nt], 0, 0, 0);
            accN[4 + nt] = __builtin_amdgcn_mfma_f32_16x16x32_f16(fA1, wB, accN[4 + nt], 0, 0, 0);
        }
    }
    float b1v[4];
#pragma unroll
    for (int nt = 0; nt < 4; nt++) b1v[nt] = b1[nt * 16 + r16];
#pragma unroll
    for (int mt = 0; mt < 2; mt++) {
#pragma unroll
        for (int i = 0; i < 4; i++) {
            int nl = wave * 32 + mt * 16 + quad * 4 + i;
#pragma unroll
            for (int nt = 0; nt < 4; nt++) {
                float v = fmaxf(accN[mt * 4 + nt][i] + b1v[nt], 0.f);
                bufB[nl * 72 + nt * 16 + r16] = (_Float16)v;
            }
        }
    }
    __syncthreads();

    // ---------------- Phase 3: nn2 (relu(u @ W2 + b2)) -> bufA + bnstat partials
    f32x4 accM[8];
#pragma unroll
    for (int i = 0; i < 8; i++) accM[i] = (f32x4){0.f, 0.f, 0.f, 0.f};
#pragma unroll
    for (int s = 0; s < 2; s++) {
        f16x8 fA0 = *(const f16x8*)(bufB + (wave * 32 + r16) * 72 + s * 32 + quad * 8);
        f16x8 fA1 = *(const f16x8*)(bufB + (wave * 32 + 16 + r16) * 72 + s * 32 + quad * 8);
#pragma unroll
        for (int nt = 0; nt < 4; nt++) {
            f16x8 wB = *(const f16x8*)((const _Float16*)w2F + (size_t)(nt * 16 + r16) * 64
                                       + s * 32 + quad * 8);
            accM[nt]     = __builtin_amdgcn_mfma_f32_16x16x32_f16(fA0, wB, accM[nt], 0, 0, 0);
            accM[4 + nt] = __builtin_amdgcn_mfma_f32_16x16x32_f16(fA1, wB, accM[4 + nt], 0, 0, 0);
        }
    }
    float b2v[4], s1[4], s2[4];
#pragma unroll
    for (int nt = 0; nt < 4; nt++) {
        b2v[nt] = b2[nt * 16 + r16]; s1[nt] = 0.f; s2[nt] = 0.f;
    }
#pragma unroll
    for (int mt = 0; mt < 2; mt++) {
#pragma unroll
        for (int i = 0; i < 4; i++) {
            int nl = wave * 32 + mt * 16 + quad * 4 + i;
            bool ok = (n0 + nl) < N;
#pragma unroll
            for (int nt = 0; nt < 4; nt++) {
                float v = fmaxf(accM[mt * 4 + nt][i] + b2v[nt], 0.f);
                if (ok) { s1[nt] += v; s2[nt] = fmaf(v, v, s2[nt]); }
                bufA[nl * 72 + nt * 16 + r16] = (_Float16)v;
            }
        }
    }
    __syncthreads();  // all bufB reads done before red (aliased) is written
#pragma unroll
    for (int nt = 0; nt < 4; nt++) {
        int row = wave * 4 + quad;
        red[row * 64 + nt * 16 + r16] = s1[nt];
        red[1024 + row * 64 + nt * 16 + r16] = s2[nt];
    }
    __syncthreads();

    // ---------------- Phase 4: coalesced store + bnstat reduce
    {
        int nl = t >> 1, fo = (t & 1) * 32;
        int gn = n0 + nl;
        if (gn < N) {
            const uint4* sp = (const uint4*)(bufA + nl * 72 + fo);
            uint4* dp = (uint4*)(hOut16 + (size_t)gn * 64 + fo);
            dp[0] = sp[0]; dp[1] = sp[1]; dp[2] = sp[2]; dp[3] = sp[3];
        }
    }
    if (t < 128) {
        int d = t & 63, part = t >> 6;
        float tot = 0.f;
#pragma unroll
        for (int r = 0; r < 16; r++) tot += red[part * 1024 + r * 64 + d];
        atomicAdd(&bnstat[part * 64 + d], tot);
    }
}

// ---------------------------------------------------------------- 64x64 GEMM (encoder only)
#define FMA16(ACC0, ACC1, ACC2, ACC3, A, W)                                \
    do {                                                                   \
        ACC0.x = fmaf(A.x, W.x, ACC0.x); ACC0.y = fmaf(A.x, W.y, ACC0.y);  \
        ACC0.z = fmaf(A.x, W.z, ACC0.z); ACC0.w = fmaf(A.x, W.w, ACC0.w);  \
        ACC1.x = fmaf(A.y, W.x, ACC1.x); ACC1.y = fmaf(A.y, W.y, ACC1.y);  \
        ACC1.z = fmaf(A.y, W.z, ACC1.z); ACC1.w = fmaf(A.y, W.w, ACC1.w);  \
        ACC2.x = fmaf(A.z, W.x, ACC2.x); ACC2.y = fmaf(A.z, W.y, ACC2.y);  \
        ACC2.z = fmaf(A.z, W.z, ACC2.z); ACC2.w = fmaf(A.z, W.w, ACC2.w);  \
        ACC3.x = fmaf(A.w, W.x, ACC3.x); ACC3.y = fmaf(A.w, W.y, ACC3.y);  \
        ACC3.z = fmaf(A.w, W.z, ACC3.z); ACC3.w = fmaf(A.w, W.w, ACC3.w);  \
    } while (0)

__global__ __launch_bounds__(256) void k_gemm64(const float* __restrict__ in,
                                                const float* __restrict__ W,
                                                const float* __restrict__ bias,
                                                unsigned short* __restrict__ out16, int N) {
    __shared__ float sInT[64][64];  // [k][node]
    __shared__ float sWT[64][64];   // [k][feat]
    int t = threadIdx.x;
    int tx = t & 15, ty = t >> 4;
    int n0 = blockIdx.x * 64;
    int c4 = tx * 4;
#pragma unroll
    for (int ch = 0; ch < 4; ch++) {
        int row = ch * 16 + ty;
        float4 v = make_float4(0.f, 0.f, 0.f, 0.f);
        if (n0 + row < N) v = *(const float4*)(in + (size_t)(n0 + row) * 64 + c4);
        sInT[c4 + 0][row] = v.x; sInT[c4 + 1][row] = v.y;
        sInT[c4 + 2][row] = v.z; sInT[c4 + 3][row] = v.w;
        float4 w = *(const float4*)(W + (size_t)row * 64 + c4);
        sWT[c4 + 0][row] = w.x; sWT[c4 + 1][row] = w.y;
        sWT[c4 + 2][row] = w.z; sWT[c4 + 3][row] = w.w;
    }
    __syncthreads();
    float4 acc0 = make_float4(0.f, 0.f, 0.f, 0.f);
    float4 acc1 = acc0, acc2 = acc0, acc3 = acc0;
#pragma unroll 8
    for (int k = 0; k < 64; k++) {
        float4 a = *(const float4*)(&sInT[k][ty * 4]);
        float4 w = *(const float4*)(&sWT[k][tx * 4]);
        FMA16(acc0, acc1, acc2, acc3, a, w);
    }
    float4 b4 = *(const float4*)(bias + tx * 4);
#pragma unroll
    for (int i = 0; i < 4; i++) {
        int n = n0 + ty * 4 + i;
        if (n < N) {
            float4 v = (i == 0) ? acc0 : (i == 1) ? acc1 : (i == 2) ? acc2 : acc3;
            v.x += b4.x; v.y += b4.y; v.z += b4.z; v.w += b4.w;
            ushort4 o;
            o.x = f2h(v.x); o.y = f2h(v.y); o.z = f2h(v.z); o.w = f2h(v.w);
            *(ushort4*)(out16 + (size_t)n * 64 + tx * 4) = o;
        }
    }
}

// ---------------------------------------------------------------- pool (batch sorted; BN fused; f16 in)
__global__ void k_pool(const unsigned short* __restrict__ h16, const int* __restrict__ batch,
                       const float* __restrict__ aff, float* __restrict__ g, int N) {
    int d = threadIdx.x & 63, r = threadIdx.x >> 6;
    float sc = aff[d], sh = aff[64 + d];
    const _Float16* hp = (const _Float16*)h16;
    int nbase = blockIdx.x * 32;
    float acc = 0.f;
    int gcur = -1;
    for (int i = 0; i < 8; i++) {
        int n = nbase + i * 4 + r;
        if (n < N) {
            int gb = batch[n];
            if (gb != gcur) {
                if (gcur >= 0) atomicAdd(&g[gcur * 64 + d], acc);
                acc = 0.f; gcur = gb;
            }
            acc += fmaf((float)hp[(size_t)n * 64 + d], sc, sh);
        }
    }
    if (gcur >= 0) atomicAdd(&g[gcur * 64 + d], acc);
}

// ---------------------------------------------------------------- head: relu(g@fc1)+fc2
__global__ void k_head(const float* __restrict__ g, const float* __restrict__ fc1W,
                       const float* __restrict__ fc1b, const float* __restrict__ fc2W,
                       const float* __restrict__ fc2b, float* __restrict__ out) {
    __shared__ float sg[64], sg1[64];
    int gi = blockIdx.x, t = threadIdx.x;
    sg[t] = g[gi * 64 + t];
    __syncthreads();
    float a = fc1b[t];
    for (int k = 0; k < 64; k++) a = fmaf(sg[k], fc1W[t * 64 + k], a);
    sg1[t] = fmaxf(a, 0.f);
    __syncthreads();
    if (t < 16) {
        float o = fc2b[t];
        for (int k = 0; k < 64; k++) o = fmaf(sg1[k], fc2W[t * 64 + k], o);
        out[gi * 16 + t] = o;
    }
}

// ---------------------------------------------------------------- launcher
extern "C" void kernel_launch(void* const* d_in, const int* in_sizes, int n_in,
                              void* d_out, int out_size, void* d_ws, size_t ws_size,
                              hipStream_t stream) {
    const float* x       = (const float*)d_in[0];
    const int*   eidx    = (const int*)d_in[1];
    const int*   batch   = (const int*)d_in[2];
    const float* encW    = (const float*)d_in[3];
    const float* encb    = (const float*)d_in[4];
    const float* nnW1    = (const float*)d_in[5];
    const float* nnb1    = (const float*)d_in[6];
    const float* nnW2    = (const float*)d_in[7];
    const float* nnb2    = (const float*)d_in[8];
    const float* mlpW    = (const float*)d_in[9];
    const float* mlpb    = (const float*)d_in[10];
    const float* bnG     = (const float*)d_in[11];
    const float* bnB     = (const float*)d_in[12];
    const float* fc1W    = (const float*)d_in[13];
    const float* fc1b    = (const float*)d_in[14];
    const float* fc2W    = (const float*)d_in[15];
    const float* fc2b    = (const float*)d_in[16];
    float* out = (float*)d_out;

    const int N = in_sizes[0] / 64;
    const int E = in_sizes[1] / 2;
    const int G = 512;
    const int* src = eidx;
    const int* dst = eidx + E;
    const int npp = (N + 7) / 8;  // nodes per XCD partition

    // workspace layout
    char* ws = (char*)d_ws;
    size_t off = 0;
    auto alloc = [&](size_t bytes) { size_t r = off; off = (off + bytes + 255) & ~(size_t)255; return r; };
    int*   deg     = (int*)(ws + alloc((size_t)(N + 1) * 4));
    int*   rowptr  = (int*)(ws + alloc((size_t)(N + 1) * 4));
    int*   bsums   = (int*)(ws + alloc(1024 * 4));
    int*   fill    = (int*)(ws + alloc((size_t)N * 4));
    int*   col     = (int*)(ws + alloc((size_t)E * 4));
    float* cnt     = (float*)(ws + alloc((size_t)N * 4));
    unsigned short* baseF = (unsigned short*)(ws + alloc((size_t)N * 256 * 2 + 131072));  // +pad for OOB tile reads
    unsigned short* hC16 = (unsigned short*)(ws + alloc((size_t)N * 64 * 2 + 32768));     // +pad
    unsigned short* mWF  = (unsigned short*)(ws + alloc((size_t)5 * 64 * 768 * 2));
    unsigned short* nW1F = (unsigned short*)(ws + alloc((size_t)5 * 64 * 64 * 2));
    unsigned short* nW2F = (unsigned short*)(ws + alloc((size_t)5 * 64 * 64 * 2));
    float* bnstats = (float*)(ws + alloc(5 * 128 * 4));
    float* affbuf  = (float*)(ws + alloc(6 * 128 * 4));
    float* gpool   = (float*)(ws + alloc((size_t)G * 64 * 4));

    hipMemsetAsync(deg, 0, (size_t)(N + 1) * 4, stream);
    hipMemsetAsync(fill, 0, (size_t)N * 4, stream);
    hipMemsetAsync(bnstats, 0, 5 * 128 * 4, stream);
    hipMemsetAsync(gpool, 0, (size_t)G * 64 * 4, stream);

    int total = N + 1;
    int nscan = (total + SCAN_B - 1) / SCAN_B;
    int ngrid64 = (N + 63) / 64;
    int ngrid128 = (N + 127) / 128;

    k_degree<<<1024, 256, 0, stream>>>(dst, deg, E, npp);
    k_scan_block<<<nscan, SCAN_B, 0, stream>>>(deg, rowptr, bsums, total);
    k_scan_tops<<<1, SCAN_B, 0, stream>>>(bsums, nscan);
    k_scan_add<<<nscan, SCAN_B, 0, stream>>>(rowptr, bsums, total);
    k_fill<<<1024, 256, 0, stream>>>(src, dst, rowptr, fill, col, E, npp);

    // cast weights to f16
    k_castw<<<240, 256, 0, stream>>>(mlpW, mWF, 61440);
    k_castw<<<20, 256, 0, stream>>>(nnW1, nW1F, 5120);
    k_castw<<<20, 256, 0, stream>>>(nnW2, nW2F, 5120);
    k_ident<<<1, 128, 0, stream>>>(affbuf);

    // encoder: hC16 = f16(x @ encW.T + encb)
    k_gemm64<<<ngrid64, 256, 0, stream>>>(x, encW, encb, hC16, N);

    for (int i = 0; i < 5; i++) {
        const float* aff = affbuf + i * 128;
        k_agg<<<(N + 7) / 8, 256, 0, stream>>>(hC16, rowptr, col, aff, baseF, cnt, N);
        k_mlp<<<ngrid128, 256, 0, stream>>>(baseF, cnt,
                                            mWF + (size_t)i * 64 * 768, mlpb + i * 64,
                                            hC16, aff,
                                            nW1F + (size_t)i * 4096, nnb1 + i * 64,
                                            nW2F + (size_t)i * 4096, nnb2 + i * 64,
                                            bnstats + i * 128, hC16, N);
        k_bnfin<<<1, 64, 0, stream>>>(bnstats + i * 128, bnG + i * 64, bnB + i * 64,
                                      affbuf + (i + 1) * 128, 1.f / (float)N);
    }

    k_pool<<<(N + 31) / 32, 256, 0, stream>>>(hC16, batch, affbuf + 5 * 128, gpool, N);
    k_head<<<G, 64, 0, stream>>>(gpool, fc1W, fc1b, fc2W, fc2b, out);
}